// Round 6
// baseline (641.232 us; speedup 1.0000x reference)
//
#include <hip/hip_runtime.h>

#define N_NODES 100000
#define N_EDGES 625000
#define HIDDEN 128
#define NUM_GRAPHS 512
#define CAP 40       // max in-degree capacity; Poisson(6.25) => P(deg>40) ~ e-43
#define PADN 100096  // multiple of 256

#define BUILD_BLKS 2443   // ceil(625000/256)
#define EMBED_BLKS 6250   // N_NODES*16/256
#define WT_BLKS 64        // 8 mats x 8 chunks

typedef unsigned int uint;
typedef unsigned short ushort;
typedef short v8s __attribute__((ext_vector_type(8)));
typedef float v16f __attribute__((ext_vector_type(16)));
typedef int v4i __attribute__((ext_vector_type(4)));
typedef uint v4u __attribute__((ext_vector_type(4)));

// h/t layout: 8 column-slices, hs[s][n][16] bf16; slice s = cols [16s,16s+16).
// Each slice = 3.2MB contiguous -> fits one XCD's 4MB L2.
#define SL_U4 ((size_t)N_NODES * 2)          // uint4 per slice
#define SL_US ((size_t)N_NODES * 16)         // ushort per slice

__device__ __forceinline__ float b2f_lo(uint u) { return __uint_as_float(u << 16); }
__device__ __forceinline__ float b2f_hi(uint u) { return __uint_as_float(u & 0xffff0000u); }
__device__ __forceinline__ uint f2b(float f) {  // RNE f32 -> bf16 bits
  uint u = __float_as_uint(f);
  return (u + 0x7fffu + ((u >> 16) & 1u)) >> 16;
}

// ---------------- fused prep: build adjacency + embed + weight-quantize ----------------
__global__ __launch_bounds__(256) void prep_k(const int* __restrict__ src,
                                              const int* __restrict__ dst,
                                              int* __restrict__ cursor,
                                              int* __restrict__ slots,
                                              const int* __restrict__ x,
                                              const float* __restrict__ emb,
                                              ushort* __restrict__ h,
                                              const float* __restrict__ W1,
                                              const float* __restrict__ W2,
                                              ushort* __restrict__ Wt) {
  int blk = blockIdx.x;
  int tid = threadIdx.x;
  if (blk < BUILD_BLKS) {
    int e = blk * 256 + tid;
    if (e < N_EDGES) {
      int d = dst[e];
      int p = atomicAdd(&cursor[d], 1);
      if (p < CAP) slots[(size_t)d * CAP + p] = src[e];
    }
  } else if (blk < BUILD_BLKS + EMBED_BLKS) {
    int t = (blk - BUILD_BLKS) * 256 + tid;   // one 8-col chunk per thread
    int n = t >> 4;
    if (n < N_NODES) {
      int c = t & 15;
      const float4* e4 = (const float4*)(emb + (size_t)x[n] * HIDDEN + c * 8);
      float4 a = e4[0], b = e4[1];
      uint4 o;
      o.x = f2b(a.x) | (f2b(a.y) << 16);
      o.y = f2b(a.z) | (f2b(a.w) << 16);
      o.z = f2b(b.x) | (f2b(b.y) << 16);
      o.w = f2b(b.z) | (f2b(b.w) << 16);
      // slice layout: cols c*8..c*8+7 -> slice c>>1, half c&1
      ((uint4*)h)[(size_t)(c >> 1) * SL_U4 + (size_t)n * 2 + (c & 1)] = o;
    }
  } else {
    int wb = blk - BUILD_BLKS - EMBED_BLKS;   // 0..63
    int mat = wb >> 3, chunk = wb & 7;
    const float* W = ((mat & 1) ? W2 : W1) + (size_t)(mat >> 1) * 16384;
    ushort* o = Wt + (size_t)mat * 16384;
#pragma unroll
    for (int jj = 0; jj < 8; jj++) {
      int idx = chunk * 2048 + tid + 256 * jj;  // coalesced read W[k][n]
      int k = idx >> 7, n = idx & 127;
      int c = n >> 5, l31 = n & 31;
      int ks = k >> 4, khalf = (k >> 3) & 1, e = k & 7;
      // fragment-ordered: slot s=c*8+ks, lane=khalf*32+l31, elem e
      o[(((c * 8 + ks) << 6) + (khalf << 5) + l31) * 8 + e] = (ushort)f2b(W[idx]);
    }
  }
}

// ---------------- degree-grouped permutation, two-level (LDS-aggregated) ----------------
__global__ __launch_bounds__(256) void hist_k(const int* __restrict__ cursor,
                                              int* __restrict__ bins) {
  __shared__ int lb[CAP + 1];
  int tid = threadIdx.x;
  if (tid <= CAP) lb[tid] = 0;
  __syncthreads();
  int n = blockIdx.x * 256 + tid;
  if (n < N_NODES) {
    int d = cursor[n]; if (d > CAP) d = CAP;
    atomicAdd(&lb[d], 1);                     // LDS atomic: cheap
  }
  __syncthreads();
  if (tid <= CAP && lb[tid] > 0) atomicAdd(&bins[tid], lb[tid]);  // fire-and-forget
}

__global__ __launch_bounds__(64) void scan_k(int* __restrict__ bins) {
  int i = threadIdx.x;
  int c = (i <= CAP) ? bins[i] : 0;
  int incl = c;
#pragma unroll
  for (int off = 1; off < 64; off <<= 1) {
    int t = __shfl_up(incl, off, 64);
    if (i >= off) incl += t;
  }
  if (i <= CAP) bins[i] = incl - c;           // exclusive prefix
}

// LPT dispatch: perm REVERSED (descending degree) so deg-40 blocks launch first;
// also makes each 64-lane wave of agg_k degree-homogeneous.
__global__ __launch_bounds__(256) void scatter_k(const int* __restrict__ cursor,
                                                 int* __restrict__ bins,
                                                 int* __restrict__ perm) {
  __shared__ int lb[CAP + 1];
  __shared__ int lbase[CAP + 1];
  int tid = threadIdx.x;
  if (tid <= CAP) lb[tid] = 0;
  __syncthreads();
  int n = blockIdx.x * 256 + tid;
  int d = 0, rank = 0;
  bool real = (n < N_NODES);
  if (real) {
    d = cursor[n]; if (d > CAP) d = CAP;
    rank = atomicAdd(&lb[d], 1);
  }
  __syncthreads();
  if (tid <= CAP) {
    int c = lb[tid];
    lbase[tid] = c > 0 ? atomicAdd(&bins[tid], c) : 0;
  }
  __syncthreads();
  if (real) perm[(N_NODES - 1) - (lbase[d] + rank)] = n;   // descending degree
  else if (n < PADN) perm[n] = 0;
}

// ---------------- split layer, stage 1: XCD-sliced gather ----------------
// R16: slice = blockIdx.x & 7 pins each column-slice to one XCD (round-robin
// dispatch). All neighbor reads on an XCD touch only its 3.2MB slice -> L2-hit
// after compulsory fill. Index traffic (perm/cursor/slots) nontemporal so it
// doesn't evict the slice; t1 stores nontemporal (consumed by gemm_k from L3).
// One thread = one destination row-slice (16 cols, acc = 16 f32), depth-4
// per-lane pipeline. Add order: self first, then slot order == R4 (bit-identical).
union U { uint4 u; v8s s; };

__device__ __forceinline__ void ld2(uint4 d[2], const uint4* __restrict__ rp) {
  d[0] = rp[0];
  d[1] = rp[1];
}

__device__ __forceinline__ void ac2(const uint4 u[2], float acc[16]) {
#pragma unroll
  for (int k = 0; k < 2; k++) {
    acc[k * 8 + 0] += b2f_lo(u[k].x); acc[k * 8 + 1] += b2f_hi(u[k].x);
    acc[k * 8 + 2] += b2f_lo(u[k].y); acc[k * 8 + 3] += b2f_hi(u[k].y);
    acc[k * 8 + 4] += b2f_lo(u[k].z); acc[k * 8 + 5] += b2f_hi(u[k].z);
    acc[k * 8 + 6] += b2f_lo(u[k].w); acc[k * 8 + 7] += b2f_hi(u[k].w);
  }
}

__global__ __launch_bounds__(256, 4) void agg_k(const ushort* __restrict__ hin,
                                                const int* __restrict__ cursor,
                                                const int* __restrict__ slots,
                                                const int* __restrict__ perm,
                                                ushort* __restrict__ t1) {
  int s = blockIdx.x & 7;                     // slice == XCD under %8 round-robin
  int g = blockIdx.x >> 3;                    // destination group 0..390
  int pidx = g * 256 + threadIdx.x;           // perm index (<= PADN-1)
  if (pidx >= N_NODES) return;
  int prow = __builtin_nontemporal_load(perm + pidx);
  int deg = __builtin_nontemporal_load(cursor + prow);
  if (deg > CAP) deg = CAP;
  const uint4* sb = (const uint4*)hin + (size_t)s * SL_U4;   // slice base, row stride 2
  const v4i* slv = (const v4i*)(slots + (size_t)prow * CAP); // chunks 0..9

  float acc[16];
  uint4 P0[2], P1[2], P2[2], P3[2];
  v4i ck = __builtin_nontemporal_load(slv);       // slots 0..3
  v4i cn = __builtin_nontemporal_load(slv + 1);   // slots 4..7

  ld2(P3, sb + (size_t)prow * 2);                             // self
  if (deg > 0) ld2(P0, sb + (size_t)ck[0] * 2);               // row 0
  if (deg > 1) ld2(P1, sb + (size_t)ck[1] * 2);               // row 1
  if (deg > 2) ld2(P2, sb + (size_t)ck[2] * 2);               // row 2
  __builtin_amdgcn_sched_barrier(0);
#pragma unroll
  for (int e = 0; e < 16; e++) acc[e] = 0.f;
  ac2(P3, acc);                                               // self first

  // invariant at loop head (j % 4 == 0): P0..P2 hold rows j..j+2 (where < deg);
  // ck covers slots j..j+3, cn covers j+4..j+7.
  int j = 0;
  while (j + 4 <= deg) {
    ld2(P3, sb + (size_t)ck[3] * 2);                          // row j+3
    __builtin_amdgcn_sched_barrier(0);
    ac2(P0, acc);                                             // row j
    int ni = (j >> 2) + 2; if (ni > 9) ni = 9;                // clamp: stay in row
    v4i nx = __builtin_nontemporal_load(slv + ni);
    if (j + 4 < deg) ld2(P0, sb + (size_t)cn[0] * 2);
    __builtin_amdgcn_sched_barrier(0);
    ac2(P1, acc);                                             // row j+1
    if (j + 5 < deg) ld2(P1, sb + (size_t)cn[1] * 2);
    __builtin_amdgcn_sched_barrier(0);
    ac2(P2, acc);                                             // row j+2
    if (j + 6 < deg) ld2(P2, sb + (size_t)cn[2] * 2);
    __builtin_amdgcn_sched_barrier(0);
    ac2(P3, acc);                                             // row j+3
    ck = cn; cn = nx;
    j += 4;
  }
  if (j < deg)     ac2(P0, acc);
  if (j + 1 < deg) ac2(P1, acc);
  if (j + 2 < deg) ac2(P2, acc);

  v4u o0, o1;
  o0[0] = f2b(acc[0])  | (f2b(acc[1])  << 16);
  o0[1] = f2b(acc[2])  | (f2b(acc[3])  << 16);
  o0[2] = f2b(acc[4])  | (f2b(acc[5])  << 16);
  o0[3] = f2b(acc[6])  | (f2b(acc[7])  << 16);
  o1[0] = f2b(acc[8])  | (f2b(acc[9])  << 16);
  o1[1] = f2b(acc[10]) | (f2b(acc[11]) << 16);
  o1[2] = f2b(acc[12]) | (f2b(acc[13]) << 16);
  o1[3] = f2b(acc[14]) | (f2b(acc[15]) << 16);
  v4u* orow = (v4u*)(t1 + (size_t)s * SL_US + (size_t)prow * 16);
  __builtin_nontemporal_store(o0, orow);
  __builtin_nontemporal_store(o1, orow + 1);
}

// ---------------- split layer, stage 2: dense 2-GEMM, in-place on t ----------------
// Slice-layout reads: afr[ks] = cols ks*16+khalf*8 -> uint4 #(ks*SL_U4+row*2+khalf);
// a wave's 64 lanes cover a contiguous 1KB region per (ks) -> perfectly coalesced.
// In-place safe: one wave per block; loads retire before stores issue.
__global__ __launch_bounds__(64, 3) void gemm_k(ushort* __restrict__ t,
                                                const ushort* __restrict__ W1f,
                                                const ushort* __restrict__ W2f,
                                                const float* __restrict__ b1,
                                                const float* __restrict__ b2) {
  int lane = threadIdx.x;                     // 0..63
  int l31 = lane & 31;
  int khalf = lane >> 5;
  int rb = blockIdx.x * 32;                   // 3125 * 32 == 100000 exactly

  const uint4* tv = (const uint4*)t;
  U afr[8];
#pragma unroll
  for (int ks = 0; ks < 8; ks++)
    afr[ks].u = tv[(size_t)ks * SL_U4 + (size_t)(rb + l31) * 2 + khalf];

  // ---- GEMM1 (flipped): z^T = W1^T-as-A @ agg-as-B; lane = node row ----
  const uint4* W1v = (const uint4*)W1f;       // frag-ordered: slot*64 + lane
  v16f acc1[4] = {};
#pragma unroll
  for (int c = 0; c < 4; c++)
#pragma unroll
    for (int ks = 0; ks < 8; ks++) {
      U b; b.u = W1v[((c * 8 + ks) << 6) + lane];
      acc1[c] = __builtin_amdgcn_mfma_f32_32x32x16_bf16(b.s, afr[ks].s, acc1[c], 0, 0, 0);
    }

  // bias + relu + pack: lane holds z[r=l31][k'], k' = 32c + (reg&3) + 8*(reg>>2) + 4*khalf
  uint u[4][4][2];
#pragma unroll
  for (int c = 0; c < 4; c++)
#pragma unroll
    for (int b = 0; b < 4; b++)
#pragma unroll
      for (int ap = 0; ap < 2; ap++) {
        int r0 = 2 * ap + 4 * b, r1 = r0 + 1;
        float v0 = fmaxf(acc1[c][r0] + b1[c * 32 + 2 * ap + 8 * b + 4 * khalf], 0.f);
        float v1 = fmaxf(acc1[c][r1] + b1[c * 32 + 2 * ap + 1 + 8 * b + 4 * khalf], 0.f);
        u[c][b][ap] = f2b(v0) | (f2b(v1) << 16);
      }

  uint got[4][2][2];
#pragma unroll
  for (int c = 0; c < 4; c++)
#pragma unroll
    for (int bh = 0; bh < 2; bh++)
#pragma unroll
      for (int ap = 0; ap < 2; ap++) {
        uint send = khalf ? u[c][2 * bh][ap] : u[c][2 * bh + 1][ap];
        got[c][bh][ap] = __shfl_xor(send, 32, 64);
      }

  U az[8];
#pragma unroll
  for (int ks = 0; ks < 8; ks++) {
    uint o0 = khalf ? u[ks >> 1][2 * (ks & 1) + 1][0] : u[ks >> 1][2 * (ks & 1)][0];
    uint o1 = khalf ? u[ks >> 1][2 * (ks & 1) + 1][1] : u[ks >> 1][2 * (ks & 1)][1];
    uint g0 = got[ks >> 1][ks & 1][0];
    uint g1 = got[ks >> 1][ks & 1][1];
    az[ks].u.x = khalf ? g0 : o0;
    az[ks].u.y = khalf ? g1 : o1;
    az[ks].u.z = khalf ? o0 : g0;
    az[ks].u.w = khalf ? o1 : g1;
  }

  // ---- GEMM2 (normal): h_out = z @ W2 + b2 ----
  const uint4* W2v = (const uint4*)W2f;
  v16f acc2[4] = {};
#pragma unroll
  for (int c = 0; c < 4; c++)
#pragma unroll
    for (int ks = 0; ks < 8; ks++) {
      U b; b.u = W2v[((c * 8 + ks) << 6) + lane];
      acc2[c] = __builtin_amdgcn_mfma_f32_32x32x16_bf16(az[ks].s, b.s, acc2[c], 0, 0, 0);
    }

  float bv2[4];
#pragma unroll
  for (int c = 0; c < 4; c++) bv2[c] = b2[c * 32 + l31];
#pragma unroll
  for (int c = 0; c < 4; c++) {
    int sc = (c << 1) + (l31 >> 4);           // slice of col c*32+l31
    int cw = l31 & 15;                        // col within slice
#pragma unroll
    for (int r = 0; r < 16; r++) {
      int m = (r & 3) + 8 * (r >> 2) + 4 * khalf;
      t[(size_t)sc * SL_US + (size_t)(rb + m) * 16 + cw] = (ushort)f2b(acc2[c][r] + bv2[c]);
    }
  }
}

// ---------------- fused pool+MLP: g = segsum(h); out = mlp(g) ----------------
__global__ __launch_bounds__(256) void poolmlp_k(const ushort* __restrict__ h,
                                                 const int* __restrict__ batch,
                                                 const float* __restrict__ W1, const float* __restrict__ b1,
                                                 const float* __restrict__ W2, const float* __restrict__ b2,
                                                 const float* __restrict__ W3, const float* __restrict__ b3,
                                                 float* __restrict__ out) {
  __shared__ int se[2];
  __shared__ float red[16][16][8];
  __shared__ float gl[128];
  __shared__ float r2[64];
  __shared__ float r3[32];
  int gi = blockIdx.x, tid = threadIdx.x;
  if (tid < 2) {
    int target = gi + tid;
    int lo = 0, hi = N_NODES;
    while (lo < hi) {
      int mid = (lo + hi) >> 1;
      if (batch[mid] < target) lo = mid + 1; else hi = mid;
    }
    se[tid] = lo;
  }
  __syncthreads();
  int start = se[0], end = se[1];
  int cg = tid & 15, rg = tid >> 4;
  float acc[8] = {0.f, 0.f, 0.f, 0.f, 0.f, 0.f, 0.f, 0.f};
  // slice layout: cols cg*8..cg*8+7 = slice cg>>1, half cg&1 (same cols as before)
  size_t sbase = (size_t)(cg >> 1) * SL_U4 + (cg & 1);
  for (int r = start + rg; r < end; r += 16) {
    uint4 v = ((const uint4*)h)[sbase + (size_t)r * 2];
    acc[0] += b2f_lo(v.x); acc[1] += b2f_hi(v.x);
    acc[2] += b2f_lo(v.y); acc[3] += b2f_hi(v.y);
    acc[4] += b2f_lo(v.z); acc[5] += b2f_hi(v.z);
    acc[6] += b2f_lo(v.w); acc[7] += b2f_hi(v.w);
  }
#pragma unroll
  for (int j = 0; j < 8; j++) red[rg][cg][j] = acc[j];
  __syncthreads();
  if (rg == 0) {
    float s[8];
#pragma unroll
    for (int j = 0; j < 8; j++) s[j] = red[0][cg][j];
#pragma unroll
    for (int i = 1; i < 16; i++)
#pragma unroll
      for (int j = 0; j < 8; j++) s[j] += red[i][cg][j];
#pragma unroll
    for (int j = 0; j < 8; j++) gl[cg * 8 + j] = s[j];
  }
  __syncthreads();
  if (tid < 64) {
    float s = b1[tid];
    for (int k = 0; k < 128; k++) s = fmaf(gl[k], W1[k * 64 + tid], s);
    r2[tid] = fmaxf(s, 0.f);
  }
  __syncthreads();
  if (tid < 32) {
    float s2 = b2[tid];
    for (int k = 0; k < 64; k++) s2 = fmaf(r2[k], W2[k * 32 + tid], s2);
    r3[tid] = fmaxf(s2, 0.f);
  }
  __syncthreads();
  if (tid < 64) {
    float pv = (tid < 32) ? r3[tid] * W3[tid] : 0.f;
#pragma unroll
    for (int off = 32; off > 0; off >>= 1) pv += __shfl_down(pv, off);
    if (tid == 0) out[gi] = pv + b3[0];
  }
}

extern "C" void kernel_launch(void* const* d_in, const int* in_sizes, int n_in,
                              void* d_out, int out_size, void* d_ws, size_t ws_size,
                              hipStream_t stream) {
  const int* x = (const int*)d_in[0];
  const int* src = (const int*)d_in[1];
  const int* dst = src + N_EDGES;
  const int* batch = (const int*)d_in[3];
  const float* node_emb = (const float*)d_in[4];
  const float* cW1 = (const float*)d_in[6];
  const float* cb1 = (const float*)d_in[7];
  const float* cW2 = (const float*)d_in[8];
  const float* cb2 = (const float*)d_in[9];
  const float* mW1 = (const float*)d_in[10];
  const float* mb1 = (const float*)d_in[11];
  const float* mW2 = (const float*)d_in[12];
  const float* mb2 = (const float*)d_in[13];
  const float* mW3 = (const float*)d_in[14];
  const float* mb3 = (const float*)d_in[15];
  float* out = (float*)d_out;

  char* p = (char*)d_ws;
  const size_t HB = (size_t)N_NODES * HIDDEN * sizeof(ushort);  // 25.6 MB
  ushort* h = (ushort*)p;      p += HB;
  ushort* t0 = (ushort*)p;     p += HB;
  ushort* Wtb = (ushort*)p;    p += (size_t)8 * 16384 * sizeof(ushort);
  int* cursor = (int*)p;       p += (size_t)N_NODES * sizeof(int);
  int* bins = (int*)p;         p += 64 * sizeof(int);
  int* slots = (int*)p;        p += (size_t)N_NODES * CAP * sizeof(int);
  int* perm = (int*)p;         p += (size_t)PADN * sizeof(int);

  (void)hipMemsetAsync(cursor, 0, ((size_t)N_NODES + 64) * sizeof(int), stream);  // cursor + bins
  prep_k<<<BUILD_BLKS + EMBED_BLKS + WT_BLKS, 256, 0, stream>>>(
      src, dst, cursor, slots, x, node_emb, h, cW1, cW2, Wtb);
  hist_k<<<PADN / 256, 256, 0, stream>>>(cursor, bins);
  scan_k<<<1, 64, 0, stream>>>(bins);
  scatter_k<<<PADN / 256, 256, 0, stream>>>(cursor, bins, perm);

  ushort* bufs[2] = {h, t0};
  for (int l = 0; l < 4; l++) {
    ushort* in = bufs[l & 1];
    ushort* tmp = bufs[(l & 1) ^ 1];
    agg_k<<<8 * (PADN / 256), 256, 0, stream>>>(in, cursor, slots, perm, tmp);
    gemm_k<<<N_NODES / 32, 64, 0, stream>>>(tmp,
                                            Wtb + (size_t)(2 * l) * 16384,
                                            Wtb + (size_t)(2 * l + 1) * 16384,
                                            cb1 + (size_t)l * HIDDEN,
                                            cb2 + (size_t)l * HIDDEN);
  }
  // after 4 layers output is back in h (bufs[0])
  poolmlp_k<<<NUM_GRAPHS, 256, 0, stream>>>(h, batch, mW1, mb1, mW2, mb2, mW3, mb3, out);
}

// Round 7
// 374.576 us; speedup vs baseline: 1.7119x; 1.7119x over previous
//
#include <hip/hip_runtime.h>

#define N_NODES 100000
#define N_EDGES 625000
#define HIDDEN 128
#define NUM_GRAPHS 512
#define CAP 40       // max in-degree capacity; Poisson(6.25) => P(deg>40) ~ e-43
#define PADN 100096  // multiple of 256; 3128 gather-chunks of 32

#define BUILD_BLKS 2443   // ceil(625000/256)
#define EMBED_BLKS 6250   // N_NODES*16/256
#define WT_BLKS 64        // 8 mats x 8 chunks

typedef unsigned int uint;
typedef unsigned short ushort;
typedef short v8s __attribute__((ext_vector_type(8)));
typedef float v16f __attribute__((ext_vector_type(16)));

__device__ __forceinline__ float b2f_lo(uint u) { return __uint_as_float(u << 16); }
__device__ __forceinline__ float b2f_hi(uint u) { return __uint_as_float(u & 0xffff0000u); }
__device__ __forceinline__ uint f2b(float f) {  // RNE f32 -> bf16 bits
  uint u = __float_as_uint(f);
  return (u + 0x7fffu + ((u >> 16) & 1u)) >> 16;
}

// ---------------- fused prep: build adjacency + embed + weight-quantize ----------------
__global__ __launch_bounds__(256) void prep_k(const int* __restrict__ src,
                                              const int* __restrict__ dst,
                                              int* __restrict__ cursor,
                                              int* __restrict__ slots,
                                              const int* __restrict__ x,
                                              const float* __restrict__ emb,
                                              ushort* __restrict__ h,
                                              const float* __restrict__ W1,
                                              const float* __restrict__ W2,
                                              ushort* __restrict__ Wt) {
  int blk = blockIdx.x;
  int tid = threadIdx.x;
  if (blk < BUILD_BLKS) {
    int e = blk * 256 + tid;
    if (e < N_EDGES) {
      int d = dst[e];
      int p = atomicAdd(&cursor[d], 1);
      if (p < CAP) slots[(size_t)d * CAP + p] = src[e];
    }
  } else if (blk < BUILD_BLKS + EMBED_BLKS) {
    int t = (blk - BUILD_BLKS) * 256 + tid;   // one 8-col chunk per thread
    int n = t >> 4;
    if (n < N_NODES) {
      int c = t & 15;
      const float4* e4 = (const float4*)(emb + (size_t)x[n] * HIDDEN + c * 8);
      float4 a = e4[0], b = e4[1];
      uint4 o;
      o.x = f2b(a.x) | (f2b(a.y) << 16);
      o.y = f2b(a.z) | (f2b(a.w) << 16);
      o.z = f2b(b.x) | (f2b(b.y) << 16);
      o.w = f2b(b.z) | (f2b(b.w) << 16);
      ((uint4*)h)[t] = o;
    }
  } else {
    int wb = blk - BUILD_BLKS - EMBED_BLKS;   // 0..63
    int mat = wb >> 3, chunk = wb & 7;
    const float* W = ((mat & 1) ? W2 : W1) + (size_t)(mat >> 1) * 16384;
    ushort* o = Wt + (size_t)mat * 16384;
#pragma unroll
    for (int jj = 0; jj < 8; jj++) {
      int idx = chunk * 2048 + tid + 256 * jj;  // coalesced read W[k][n]
      int k = idx >> 7, n = idx & 127;
      int c = n >> 5, l31 = n & 31;
      int ks = k >> 4, khalf = (k >> 3) & 1, e = k & 7;
      // fragment-ordered: slot s=c*8+ks, lane=khalf*32+l31, elem e
      o[(((c * 8 + ks) << 6) + (khalf << 5) + l31) * 8 + e] = (ushort)f2b(W[idx]);
    }
  }
}

// ---------------- degree-grouped permutation, two-level (LDS-aggregated) ----------------
__global__ __launch_bounds__(256) void hist_k(const int* __restrict__ cursor,
                                              int* __restrict__ bins) {
  __shared__ int lb[CAP + 1];
  int tid = threadIdx.x;
  if (tid <= CAP) lb[tid] = 0;
  __syncthreads();
  int n = blockIdx.x * 256 + tid;
  if (n < N_NODES) {
    int d = cursor[n]; if (d > CAP) d = CAP;
    atomicAdd(&lb[d], 1);                     // LDS atomic: cheap
  }
  __syncthreads();
  if (tid <= CAP && lb[tid] > 0) atomicAdd(&bins[tid], lb[tid]);  // fire-and-forget
}

__global__ __launch_bounds__(64) void scan_k(int* __restrict__ bins) {
  int i = threadIdx.x;
  int c = (i <= CAP) ? bins[i] : 0;
  int incl = c;
#pragma unroll
  for (int off = 1; off < 64; off <<= 1) {
    int t = __shfl_up(incl, off, 64);
    if (i >= off) incl += t;
  }
  if (i <= CAP) bins[i] = incl - c;           // exclusive prefix
}

// LPT dispatch: perm REVERSED (descending degree) so deg-40 blocks launch first;
// also makes each 32-row tile degree-homogeneous.
__global__ __launch_bounds__(256) void scatter_k(const int* __restrict__ cursor,
                                                 int* __restrict__ bins,
                                                 int* __restrict__ perm) {
  __shared__ int lb[CAP + 1];
  __shared__ int lbase[CAP + 1];
  int tid = threadIdx.x;
  if (tid <= CAP) lb[tid] = 0;
  __syncthreads();
  int n = blockIdx.x * 256 + tid;
  int d = 0, rank = 0;
  bool real = (n < N_NODES);
  if (real) {
    d = cursor[n]; if (d > CAP) d = CAP;
    rank = atomicAdd(&lb[d], 1);
  }
  __syncthreads();
  if (tid <= CAP) {
    int c = lb[tid];
    lbase[tid] = c > 0 ? atomicAdd(&bins[tid], c) : 0;
  }
  __syncthreads();
  if (real) perm[(N_NODES - 1) - (lbase[d] + rank)] = n;   // descending degree
  else if (n < PADN) perm[n] = 0;
}

// ---------------- fused layer: h_out = (relu((agg+h)@W1+b1))@W2 + b2 ----------------
// R17 = R0 baseline with LINE-OPTIMAL gather shape. Old loadrow touched each
// 128B line of h 4x (8 scattered 16B chunks per lane across 8 instrs). New:
// lane=(r8,q) owns 32B contiguous of one row per group; wave covers 32 rows as
// 4 groups of 8; each line touched exactly ONCE -> 4x fewer L1/L2 transactions,
// same bytes, same depth-2 A/B pipeline, same f32 add order (self, slot 0,1,..)
// -> bit-identical sums. Rounded bf16 crosses to MFMA A-frag layout via padded
// LDS (272B row stride; single wave, no barrier). GEMM path unchanged.
union U { uint4 u; v8s s; };

__device__ __forceinline__ void acc_set(const uint4 u[2], float a[16]) {
#pragma unroll
  for (int k = 0; k < 2; k++) {
    a[k * 8 + 0] = b2f_lo(u[k].x); a[k * 8 + 1] = b2f_hi(u[k].x);
    a[k * 8 + 2] = b2f_lo(u[k].y); a[k * 8 + 3] = b2f_hi(u[k].y);
    a[k * 8 + 4] = b2f_lo(u[k].z); a[k * 8 + 5] = b2f_hi(u[k].z);
    a[k * 8 + 6] = b2f_lo(u[k].w); a[k * 8 + 7] = b2f_hi(u[k].w);
  }
}

__device__ __forceinline__ void acc_add(const uint4 u[2], float a[16]) {
#pragma unroll
  for (int k = 0; k < 2; k++) {
    a[k * 8 + 0] += b2f_lo(u[k].x); a[k * 8 + 1] += b2f_hi(u[k].x);
    a[k * 8 + 2] += b2f_lo(u[k].y); a[k * 8 + 3] += b2f_hi(u[k].y);
    a[k * 8 + 4] += b2f_lo(u[k].z); a[k * 8 + 5] += b2f_hi(u[k].z);
    a[k * 8 + 6] += b2f_lo(u[k].w); a[k * 8 + 7] += b2f_hi(u[k].w);
  }
}

__global__ __launch_bounds__(64, 3) void layer_k(const ushort* __restrict__ hin,
                                                 const int* __restrict__ cursor,
                                                 const int* __restrict__ slots,
                                                 const int* __restrict__ perm,
                                                 const ushort* __restrict__ W1f,
                                                 const ushort* __restrict__ W2f,
                                                 const float* __restrict__ b1,
                                                 const float* __restrict__ b2,
                                                 ushort* __restrict__ hout) {
  __shared__ uint4 xchv[32 * 17];             // 32 rows x 272B (16 data + 1 pad uint4)
  int lane = threadIdx.x;                     // 0..63
  int q = lane & 7;                           // column-eighth (32B of a row)
  int r8 = lane >> 3;                         // row within group
  int tb = blockIdx.x * 32;                   // tile base in perm order

  // ---- gather: 4 groups x 8 rows, line-optimal ----
  int prow[4], deg[4];
#pragma unroll
  for (int g = 0; g < 4; g++) {
    int idx = tb + g * 8 + r8;
    bool v = idx < N_NODES;
    prow[g] = v ? perm[idx] : 0;
    int d = v ? cursor[prow[g]] : 0;
    if (d > CAP) d = CAP;
    deg[g] = d;
  }
  const uint4* base = (const uint4*)hin;      // 16 uint4 per 128-col row

  float acc[4][16];
  uint4 A[4][2], B[4][2];
  int sj1[4];

#pragma unroll
  for (int g = 0; g < 4; g++) {               // self rows -> A
    const uint4* rp = base + (size_t)prow[g] * 16 + q * 2;
    A[g][0] = rp[0]; A[g][1] = rp[1];
  }
#pragma unroll
  for (int g = 0; g < 4; g++) {               // nbr 0 -> B; prefetch slot 1
    if (deg[g] > 0) {
      int s0 = slots[(size_t)prow[g] * CAP];
      const uint4* rp = base + (size_t)s0 * 16 + q * 2;
      B[g][0] = rp[0]; B[g][1] = rp[1];
    }
    sj1[g] = (deg[g] > 1) ? slots[(size_t)prow[g] * CAP + 1] : 0;
  }
  __builtin_amdgcn_sched_barrier(0);
#pragma unroll
  for (int g = 0; g < 4; g++) acc_set(A[g], acc[g]);          // self first

  int md = max(max(deg[0], deg[1]), max(deg[2], deg[3]));
  int j = 0;
  while (j + 2 <= md) {
#pragma unroll
    for (int g = 0; g < 4; g++)                               // row j+1 -> A
      if (j + 1 < deg[g]) {
        const uint4* rp = base + (size_t)sj1[g] * 16 + q * 2;
        A[g][0] = rp[0]; A[g][1] = rp[1];
      }
    int sj2[4];
#pragma unroll
    for (int g = 0; g < 4; g++)
      sj2[g] = (j + 2 < deg[g]) ? slots[(size_t)prow[g] * CAP + j + 2] : 0;
    __builtin_amdgcn_sched_barrier(0);
#pragma unroll
    for (int g = 0; g < 4; g++) if (j < deg[g]) acc_add(B[g], acc[g]);      // row j
#pragma unroll
    for (int g = 0; g < 4; g++)                               // row j+2 -> B
      if (j + 2 < deg[g]) {
        const uint4* rp = base + (size_t)sj2[g] * 16 + q * 2;
        B[g][0] = rp[0]; B[g][1] = rp[1];
      }
#pragma unroll
    for (int g = 0; g < 4; g++)
      sj1[g] = (j + 3 < deg[g]) ? slots[(size_t)prow[g] * CAP + j + 3] : 0;
    __builtin_amdgcn_sched_barrier(0);
#pragma unroll
    for (int g = 0; g < 4; g++) if (j + 1 < deg[g]) acc_add(A[g], acc[g]);  // row j+1
    j += 2;
  }
  if (j < md) {
#pragma unroll
    for (int g = 0; g < 4; g++) if (j < deg[g]) acc_add(B[g], acc[g]);      // last row
  }

  // ---- round to bf16 (same rounding point as baseline), stage through LDS ----
#pragma unroll
  for (int g = 0; g < 4; g++) {
    int row = g * 8 + r8;
    uint4 o0, o1;
    o0.x = f2b(acc[g][0])  | (f2b(acc[g][1])  << 16);
    o0.y = f2b(acc[g][2])  | (f2b(acc[g][3])  << 16);
    o0.z = f2b(acc[g][4])  | (f2b(acc[g][5])  << 16);
    o0.w = f2b(acc[g][6])  | (f2b(acc[g][7])  << 16);
    o1.x = f2b(acc[g][8])  | (f2b(acc[g][9])  << 16);
    o1.y = f2b(acc[g][10]) | (f2b(acc[g][11]) << 16);
    o1.z = f2b(acc[g][12]) | (f2b(acc[g][13]) << 16);
    o1.w = f2b(acc[g][14]) | (f2b(acc[g][15]) << 16);
    xchv[row * 17 + 2 * q] = o0;              // cols q*16..q*16+7
    xchv[row * 17 + 2 * q + 1] = o1;          // cols q*16+8..q*16+15
  }
  // single wave: compiler inserts lgkmcnt for the LDS RAW below; no barrier needed

  int l31 = lane & 31;
  int khalf = lane >> 5;
  U afr[8];
#pragma unroll
  for (int ks = 0; ks < 8; ks++)              // row l31, cols ks*16+khalf*8 ..+7
    afr[ks].u = xchv[l31 * 17 + 2 * ks + khalf];

  // ---- GEMM1 (flipped): z^T = W1^T-as-A @ agg-as-B; lane = node row ----
  const uint4* W1v = (const uint4*)W1f;       // frag-ordered: slot*64 + lane
  v16f acc1[4] = {};
#pragma unroll
  for (int c = 0; c < 4; c++)
#pragma unroll
    for (int ks = 0; ks < 8; ks++) {
      U b; b.u = W1v[((c * 8 + ks) << 6) + lane];
      acc1[c] = __builtin_amdgcn_mfma_f32_32x32x16_bf16(b.s, afr[ks].s, acc1[c], 0, 0, 0);
    }

  // bias + relu + pack: lane holds z[r=l31][k'], k' = 32c + (reg&3) + 8*(reg>>2) + 4*khalf
  uint u[4][4][2];
#pragma unroll
  for (int c = 0; c < 4; c++)
#pragma unroll
    for (int b = 0; b < 4; b++)
#pragma unroll
      for (int ap = 0; ap < 2; ap++) {
        int r0 = 2 * ap + 4 * b, r1 = r0 + 1;
        float v0 = fmaxf(acc1[c][r0] + b1[c * 32 + 2 * ap + 8 * b + 4 * khalf], 0.f);
        float v1 = fmaxf(acc1[c][r1] + b1[c * 32 + 2 * ap + 1 + 8 * b + 4 * khalf], 0.f);
        u[c][b][ap] = f2b(v0) | (f2b(v1) << 16);
      }

  uint got[4][2][2];
#pragma unroll
  for (int c = 0; c < 4; c++)
#pragma unroll
    for (int bh = 0; bh < 2; bh++)
#pragma unroll
      for (int ap = 0; ap < 2; ap++) {
        uint send = khalf ? u[c][2 * bh][ap] : u[c][2 * bh + 1][ap];
        got[c][bh][ap] = __shfl_xor(send, 32, 64);
      }

  U az[8];
#pragma unroll
  for (int ks = 0; ks < 8; ks++) {
    uint o0 = khalf ? u[ks >> 1][2 * (ks & 1) + 1][0] : u[ks >> 1][2 * (ks & 1)][0];
    uint o1 = khalf ? u[ks >> 1][2 * (ks & 1) + 1][1] : u[ks >> 1][2 * (ks & 1)][1];
    uint g0 = got[ks >> 1][ks & 1][0];
    uint g1 = got[ks >> 1][ks & 1][1];
    az[ks].u.x = khalf ? g0 : o0;
    az[ks].u.y = khalf ? g1 : o1;
    az[ks].u.z = khalf ? o0 : g0;
    az[ks].u.w = khalf ? o1 : g1;
  }

  // ---- GEMM2 (normal): h_out = z @ W2 + b2 ----
  const uint4* W2v = (const uint4*)W2f;
  v16f acc2[4] = {};
#pragma unroll
  for (int c = 0; c < 4; c++)
#pragma unroll
    for (int ks = 0; ks < 8; ks++) {
      U b; b.u = W2v[((c * 8 + ks) << 6) + lane];
      acc2[c] = __builtin_amdgcn_mfma_f32_32x32x16_bf16(az[ks].s, b.s, acc2[c], 0, 0, 0);
    }

  int prowst = perm[tb + l31];                // store-phase row (per l31, as baseline)
  int trow[16];
#pragma unroll
  for (int r = 0; r < 16; r++) {
    int m = (r & 3) + 8 * (r >> 2) + 4 * khalf;
    trow[r] = __shfl(prowst, m, 64);
  }
  float bv2[4];
#pragma unroll
  for (int c = 0; c < 4; c++) bv2[c] = b2[c * 32 + l31];
#pragma unroll
  for (int c = 0; c < 4; c++) {
    int col = c * 32 + l31;
#pragma unroll
    for (int r = 0; r < 16; r++) {
      int m = (r & 3) + 8 * (r >> 2) + 4 * khalf;
      if (tb + m < N_NODES)
        hout[(size_t)trow[r] * HIDDEN + col] = (ushort)f2b(acc2[c][r] + bv2[c]);
    }
  }
}

// ---------------- fused pool+MLP: g = segsum(h); out = mlp(g) ----------------
__global__ __launch_bounds__(256) void poolmlp_k(const ushort* __restrict__ h,
                                                 const int* __restrict__ batch,
                                                 const float* __restrict__ W1, const float* __restrict__ b1,
                                                 const float* __restrict__ W2, const float* __restrict__ b2,
                                                 const float* __restrict__ W3, const float* __restrict__ b3,
                                                 float* __restrict__ out) {
  __shared__ int se[2];
  __shared__ float red[16][16][8];
  __shared__ float gl[128];
  __shared__ float r2[64];
  __shared__ float r3[32];
  int gi = blockIdx.x, tid = threadIdx.x;
  if (tid < 2) {
    int target = gi + tid;
    int lo = 0, hi = N_NODES;
    while (lo < hi) {
      int mid = (lo + hi) >> 1;
      if (batch[mid] < target) lo = mid + 1; else hi = mid;
    }
    se[tid] = lo;
  }
  __syncthreads();
  int start = se[0], end = se[1];
  int cg = tid & 15, rg = tid >> 4;
  float acc[8] = {0.f, 0.f, 0.f, 0.f, 0.f, 0.f, 0.f, 0.f};
  for (int r = start + rg; r < end; r += 16) {
    uint4 v = ((const uint4*)h)[r * 16 + cg];
    acc[0] += b2f_lo(v.x); acc[1] += b2f_hi(v.x);
    acc[2] += b2f_lo(v.y); acc[3] += b2f_hi(v.y);
    acc[4] += b2f_lo(v.z); acc[5] += b2f_hi(v.z);
    acc[6] += b2f_lo(v.w); acc[7] += b2f_hi(v.w);
  }
#pragma unroll
  for (int j = 0; j < 8; j++) red[rg][cg][j] = acc[j];
  __syncthreads();
  if (rg == 0) {
    float s[8];
#pragma unroll
    for (int j = 0; j < 8; j++) s[j] = red[0][cg][j];
#pragma unroll
    for (int i = 1; i < 16; i++)
#pragma unroll
      for (int j = 0; j < 8; j++) s[j] += red[i][cg][j];
#pragma unroll
    for (int j = 0; j < 8; j++) gl[cg * 8 + j] = s[j];
  }
  __syncthreads();
  if (tid < 64) {
    float s = b1[tid];
    for (int k = 0; k < 128; k++) s = fmaf(gl[k], W1[k * 64 + tid], s);
    r2[tid] = fmaxf(s, 0.f);
  }
  __syncthreads();
  if (tid < 32) {
    float s2 = b2[tid];
    for (int k = 0; k < 64; k++) s2 = fmaf(r2[k], W2[k * 32 + tid], s2);
    r3[tid] = fmaxf(s2, 0.f);
  }
  __syncthreads();
  if (tid < 64) {
    float pv = (tid < 32) ? r3[tid] * W3[tid] : 0.f;
#pragma unroll
    for (int off = 32; off > 0; off >>= 1) pv += __shfl_down(pv, off);
    if (tid == 0) out[gi] = pv + b3[0];
  }
}

extern "C" void kernel_launch(void* const* d_in, const int* in_sizes, int n_in,
                              void* d_out, int out_size, void* d_ws, size_t ws_size,
                              hipStream_t stream) {
  const int* x = (const int*)d_in[0];
  const int* src = (const int*)d_in[1];
  const int* dst = src + N_EDGES;
  const int* batch = (const int*)d_in[3];
  const float* node_emb = (const float*)d_in[4];
  const float* cW1 = (const float*)d_in[6];
  const float* cb1 = (const float*)d_in[7];
  const float* cW2 = (const float*)d_in[8];
  const float* cb2 = (const float*)d_in[9];
  const float* mW1 = (const float*)d_in[10];
  const float* mb1 = (const float*)d_in[11];
  const float* mW2 = (const float*)d_in[12];
  const float* mb2 = (const float*)d_in[13];
  const float* mW3 = (const float*)d_in[14];
  const float* mb3 = (const float*)d_in[15];
  float* out = (float*)d_out;

  char* p = (char*)d_ws;
  const size_t HB = (size_t)N_NODES * HIDDEN * sizeof(ushort);  // 25.6 MB
  ushort* h = (ushort*)p;      p += HB;
  ushort* t0 = (ushort*)p;     p += HB;
  ushort* Wtb = (ushort*)p;    p += (size_t)8 * 16384 * sizeof(ushort);
  int* cursor = (int*)p;       p += (size_t)N_NODES * sizeof(int);
  int* bins = (int*)p;         p += 64 * sizeof(int);
  int* slots = (int*)p;        p += (size_t)N_NODES * CAP * sizeof(int);
  int* perm = (int*)p;         p += (size_t)PADN * sizeof(int);

  (void)hipMemsetAsync(cursor, 0, ((size_t)N_NODES + 64) * sizeof(int), stream);  // cursor + bins
  prep_k<<<BUILD_BLKS + EMBED_BLKS + WT_BLKS, 256, 0, stream>>>(
      src, dst, cursor, slots, x, node_emb, h, cW1, cW2, Wtb);
  hist_k<<<PADN / 256, 256, 0, stream>>>(cursor, bins);
  scan_k<<<1, 64, 0, stream>>>(bins);
  scatter_k<<<PADN / 256, 256, 0, stream>>>(cursor, bins, perm);

  const int grid = PADN / 32;  // 3128 one-wave blocks
  ushort* bufs[2] = {h, t0};
  for (int l = 0; l < 4; l++) {
    layer_k<<<grid, 64, 0, stream>>>(bufs[l & 1], cursor, slots, perm,
                                     Wtb + (size_t)(2 * l) * 16384,
                                     Wtb + (size_t)(2 * l + 1) * 16384,
                                     cb1 + (size_t)l * HIDDEN,
                                     cb2 + (size_t)l * HIDDEN,
                                     bufs[(l & 1) ^ 1]);
  }
  // after 4 layers output is back in h (bufs[0])
  poolmlp_k<<<NUM_GRAPHS, 256, 0, stream>>>(h, batch, mW1, mb1, mW2, mb2, mW3, mb3, out);
}

// Round 8
// 357.270 us; speedup vs baseline: 1.7948x; 1.0484x over previous
//
#include <hip/hip_runtime.h>

#define N_NODES 100000
#define N_EDGES 625000
#define HIDDEN 128
#define NUM_GRAPHS 512
#define CAP 40       // max in-degree capacity; Poisson(6.25) => P(deg>40) ~ e-43
#define PADN 100096  // multiple of 256

#define BUILD_BLKS 2443   // ceil(625000/256)
#define EMBED_BLKS 6250   // N_NODES*16/256
#define WT_BLKS 64        // 8 mats x 8 chunks

typedef unsigned int uint;
typedef unsigned short ushort;
typedef short v8s __attribute__((ext_vector_type(8)));
typedef float v16f __attribute__((ext_vector_type(16)));

__device__ __forceinline__ float b2f_lo(uint u) { return __uint_as_float(u << 16); }
__device__ __forceinline__ float b2f_hi(uint u) { return __uint_as_float(u & 0xffff0000u); }
__device__ __forceinline__ uint f2b(float f) {  // RNE f32 -> bf16 bits
  uint u = __float_as_uint(f);
  return (u + 0x7fffu + ((u >> 16) & 1u)) >> 16;
}

// ---------------- fused prep: build adjacency + embed + weight-quantize ----------------
__global__ __launch_bounds__(256) void prep_k(const int* __restrict__ src,
                                              const int* __restrict__ dst,
                                              int* __restrict__ cursor,
                                              int* __restrict__ slots,
                                              const int* __restrict__ x,
                                              const float* __restrict__ emb,
                                              ushort* __restrict__ h,
                                              const float* __restrict__ W1,
                                              const float* __restrict__ W2,
                                              ushort* __restrict__ Wt) {
  int blk = blockIdx.x;
  int tid = threadIdx.x;
  if (blk < BUILD_BLKS) {
    int e = blk * 256 + tid;
    if (e < N_EDGES) {
      int d = dst[e];
      int p = atomicAdd(&cursor[d], 1);
      if (p < CAP) slots[(size_t)d * CAP + p] = src[e];
    }
  } else if (blk < BUILD_BLKS + EMBED_BLKS) {
    int t = (blk - BUILD_BLKS) * 256 + tid;   // one 8-col chunk per thread
    int n = t >> 4;
    if (n < N_NODES) {
      int c = t & 15;
      const float4* e4 = (const float4*)(emb + (size_t)x[n] * HIDDEN + c * 8);
      float4 a = e4[0], b = e4[1];
      uint4 o;
      o.x = f2b(a.x) | (f2b(a.y) << 16);
      o.y = f2b(a.z) | (f2b(a.w) << 16);
      o.z = f2b(b.x) | (f2b(b.y) << 16);
      o.w = f2b(b.z) | (f2b(b.w) << 16);
      ((uint4*)h)[t] = o;
    }
  } else {
    int wb = blk - BUILD_BLKS - EMBED_BLKS;   // 0..63
    int mat = wb >> 3, chunk = wb & 7;
    const float* W = ((mat & 1) ? W2 : W1) + (size_t)(mat >> 1) * 16384;
    ushort* o = Wt + (size_t)mat * 16384;
#pragma unroll
    for (int jj = 0; jj < 8; jj++) {
      int idx = chunk * 2048 + tid + 256 * jj;  // coalesced read W[k][n]
      int k = idx >> 7, n = idx & 127;
      int c = n >> 5, l31 = n & 31;
      int ks = k >> 4, khalf = (k >> 3) & 1, e = k & 7;
      // fragment-ordered: slot s=c*8+ks, lane=khalf*32+l31, elem e
      o[(((c * 8 + ks) << 6) + (khalf << 5) + l31) * 8 + e] = (ushort)f2b(W[idx]);
    }
  }
}

// ---------------- degree-grouped permutation, two-level (LDS-aggregated) ----------------
__global__ __launch_bounds__(256) void hist_k(const int* __restrict__ cursor,
                                              int* __restrict__ bins) {
  __shared__ int lb[CAP + 1];
  int tid = threadIdx.x;
  if (tid <= CAP) lb[tid] = 0;
  __syncthreads();
  int n = blockIdx.x * 256 + tid;
  if (n < N_NODES) {
    int d = cursor[n]; if (d > CAP) d = CAP;
    atomicAdd(&lb[d], 1);                     // LDS atomic: cheap
  }
  __syncthreads();
  if (tid <= CAP && lb[tid] > 0) atomicAdd(&bins[tid], lb[tid]);  // fire-and-forget
}

__global__ __launch_bounds__(64) void scan_k(int* __restrict__ bins) {
  int i = threadIdx.x;
  int c = (i <= CAP) ? bins[i] : 0;
  int incl = c;
#pragma unroll
  for (int off = 1; off < 64; off <<= 1) {
    int t = __shfl_up(incl, off, 64);
    if (i >= off) incl += t;
  }
  if (i <= CAP) bins[i] = incl - c;           // exclusive prefix
}

// LPT dispatch: perm REVERSED (descending degree) so deg-40 blocks launch first;
// also makes each 64-lane wave of agg_k degree-homogeneous.
__global__ __launch_bounds__(256) void scatter_k(const int* __restrict__ cursor,
                                                 int* __restrict__ bins,
                                                 int* __restrict__ perm) {
  __shared__ int lb[CAP + 1];
  __shared__ int lbase[CAP + 1];
  int tid = threadIdx.x;
  if (tid <= CAP) lb[tid] = 0;
  __syncthreads();
  int n = blockIdx.x * 256 + tid;
  int d = 0, rank = 0;
  bool real = (n < N_NODES);
  if (real) {
    d = cursor[n]; if (d > CAP) d = CAP;
    rank = atomicAdd(&lb[d], 1);
  }
  __syncthreads();
  if (tid <= CAP) {
    int c = lb[tid];
    lbase[tid] = c > 0 ? atomicAdd(&bins[tid], c) : 0;
  }
  __syncthreads();
  if (real) perm[(N_NODES - 1) - (lbase[d] + rank)] = n;   // descending degree
  else if (n < PADN) perm[n] = 0;
}

// ---------------- split layer, stage 1: agg (gather + sum + round) ----------------
// R18 = R4 agg at the occupancy cap. FETCH is compulsory (4.1x h = cross-XCD
// duplication floor); the lever is beyond-L2 service rate, which scaled with
// waves/CU (2.65 TB/s @12 -> ~3.3 @20). (256,7): VGPR cap 73 (kernel ~55,
// depth-2 A/B ping-pong, spill-safe) -> 28 waves/CU. 8 rows/wave, 8 lanes/row,
// line-exact loads (each 128B line touched once, by 8 contiguous lanes).
// Add order: self first, then slot order -> bit-identical to R4/baseline.
union U { uint4 u; v8s s; };

__device__ __forceinline__ void acc_set2(const uint4 u[2], float a[16]) {
#pragma unroll
  for (int k = 0; k < 2; k++) {
    a[k * 8 + 0] = b2f_lo(u[k].x); a[k * 8 + 1] = b2f_hi(u[k].x);
    a[k * 8 + 2] = b2f_lo(u[k].y); a[k * 8 + 3] = b2f_hi(u[k].y);
    a[k * 8 + 4] = b2f_lo(u[k].z); a[k * 8 + 5] = b2f_hi(u[k].z);
    a[k * 8 + 6] = b2f_lo(u[k].w); a[k * 8 + 7] = b2f_hi(u[k].w);
  }
}

__device__ __forceinline__ void acc_add2(const uint4 u[2], float a[16]) {
#pragma unroll
  for (int k = 0; k < 2; k++) {
    a[k * 8 + 0] += b2f_lo(u[k].x); a[k * 8 + 1] += b2f_hi(u[k].x);
    a[k * 8 + 2] += b2f_lo(u[k].y); a[k * 8 + 3] += b2f_hi(u[k].y);
    a[k * 8 + 4] += b2f_lo(u[k].z); a[k * 8 + 5] += b2f_hi(u[k].z);
    a[k * 8 + 6] += b2f_lo(u[k].w); a[k * 8 + 7] += b2f_hi(u[k].w);
  }
}

__global__ __launch_bounds__(256, 7) void agg_k(const ushort* __restrict__ hin,
                                                const int* __restrict__ cursor,
                                                const int* __restrict__ slots,
                                                const int* __restrict__ perm,
                                                ushort* __restrict__ t1) {
  int tid = threadIdx.x;
  int lane = tid & 63;
  int w = blockIdx.x * 4 + (tid >> 6);        // global wave id; 8 perm rows each
  int r8 = lane & 7;                          // row within wave
  int q = lane >> 3;                          // column eighth (16B + 16B)
  int pidx = w * 8 + r8;                      // perm index (< PADN by grid)
  bool valid = pidx < N_NODES;
  int prow = valid ? perm[pidx] : 0;
  int deg = valid ? cursor[prow] : 0;
  if (deg > CAP) deg = CAP;
  const int* sl = slots + (size_t)prow * CAP;
  const uint4* base = (const uint4*)hin;      // 16 uint4 per 128-col row

  float acc[16];
  uint4 A[2], B[2];

  {                                            // self
    const uint4* rp = base + (size_t)prow * 16;
    A[0] = rp[q]; A[1] = rp[q + 8];
  }
  int s1 = 0;
  if (deg > 0) {                               // nbr row 0 -> B
    int s0 = sl[0];
    const uint4* rp = base + (size_t)s0 * 16;
    B[0] = rp[q]; B[1] = rp[q + 8];
  }
  if (deg > 1) s1 = sl[1];
  __builtin_amdgcn_sched_barrier(0);
  acc_set2(A, acc);                            // self first

  // invariant at loop head: B holds row j; s1 = slot j+1 (where < deg)
  int j = 0;
  while (j + 2 <= deg) {
    {                                          // row j+1 -> A
      const uint4* rp = base + (size_t)s1 * 16;
      A[0] = rp[q]; A[1] = rp[q + 8];
    }
    int s2 = (j + 2 < deg) ? sl[j + 2] : 0;
    __builtin_amdgcn_sched_barrier(0);
    acc_add2(B, acc);                          // row j
    if (j + 2 < deg) {                         // row j+2 -> B
      const uint4* rp = base + (size_t)s2 * 16;
      B[0] = rp[q]; B[1] = rp[q + 8];
    }
    s1 = (j + 3 < deg) ? sl[j + 3] : 0;
    __builtin_amdgcn_sched_barrier(0);
    acc_add2(A, acc);                          // row j+1
    j += 2;
  }
  if (j < deg) acc_add2(B, acc);               // last odd row

  if (valid) {
    uint4 o0, o1;
    o0.x = f2b(acc[0])  | (f2b(acc[1])  << 16);
    o0.y = f2b(acc[2])  | (f2b(acc[3])  << 16);
    o0.z = f2b(acc[4])  | (f2b(acc[5])  << 16);
    o0.w = f2b(acc[6])  | (f2b(acc[7])  << 16);
    o1.x = f2b(acc[8])  | (f2b(acc[9])  << 16);
    o1.y = f2b(acc[10]) | (f2b(acc[11]) << 16);
    o1.z = f2b(acc[12]) | (f2b(acc[13]) << 16);
    o1.w = f2b(acc[14]) | (f2b(acc[15]) << 16);
    uint4* orow = (uint4*)(t1 + (size_t)prow * HIDDEN);
    orow[q] = o0;
    orow[q + 8] = o1;
  }
}

// ---------------- split layer, stage 2: dense 2-GEMM, in-place on t ----------------
// Natural row order (no perm/slots): coalesced reads, coalesced writes.
// In-place safe: one wave per block; each row read only by its own block, and
// the wave's 8 loads retire (s_waitcnt before MFMA) before any store issues.
__global__ __launch_bounds__(64, 3) void gemm_k(ushort* __restrict__ t,
                                                const ushort* __restrict__ W1f,
                                                const ushort* __restrict__ W2f,
                                                const float* __restrict__ b1,
                                                const float* __restrict__ b2) {
  int lane = threadIdx.x;                     // 0..63
  int l31 = lane & 31;
  int khalf = lane >> 5;
  int rb = blockIdx.x * 32;                   // 3125 * 32 == 100000 exactly

  const uint4* rowp = (const uint4*)t + (size_t)(rb + l31) * 16;
  U afr[8];
#pragma unroll
  for (int ks = 0; ks < 8; ks++) afr[ks].u = rowp[khalf + 2 * ks];

  // ---- GEMM1 (flipped): z^T = W1^T-as-A @ agg-as-B; lane = node row ----
  const uint4* W1v = (const uint4*)W1f;       // frag-ordered: slot*64 + lane
  v16f acc1[4] = {};
#pragma unroll
  for (int c = 0; c < 4; c++)
#pragma unroll
    for (int ks = 0; ks < 8; ks++) {
      U b; b.u = W1v[((c * 8 + ks) << 6) + lane];
      acc1[c] = __builtin_amdgcn_mfma_f32_32x32x16_bf16(b.s, afr[ks].s, acc1[c], 0, 0, 0);
    }

  // bias + relu + pack: lane holds z[r=l31][k'], k' = 32c + (reg&3) + 8*(reg>>2) + 4*khalf
  uint u[4][4][2];
#pragma unroll
  for (int c = 0; c < 4; c++)
#pragma unroll
    for (int b = 0; b < 4; b++)
#pragma unroll
      for (int ap = 0; ap < 2; ap++) {
        int r0 = 2 * ap + 4 * b, r1 = r0 + 1;
        float v0 = fmaxf(acc1[c][r0] + b1[c * 32 + 2 * ap + 8 * b + 4 * khalf], 0.f);
        float v1 = fmaxf(acc1[c][r1] + b1[c * 32 + 2 * ap + 1 + 8 * b + 4 * khalf], 0.f);
        u[c][b][ap] = f2b(v0) | (f2b(v1) << 16);
      }

  uint got[4][2][2];
#pragma unroll
  for (int c = 0; c < 4; c++)
#pragma unroll
    for (int bh = 0; bh < 2; bh++)
#pragma unroll
      for (int ap = 0; ap < 2; ap++) {
        uint send = khalf ? u[c][2 * bh][ap] : u[c][2 * bh + 1][ap];
        got[c][bh][ap] = __shfl_xor(send, 32, 64);
      }

  U az[8];
#pragma unroll
  for (int ks = 0; ks < 8; ks++) {
    uint o0 = khalf ? u[ks >> 1][2 * (ks & 1) + 1][0] : u[ks >> 1][2 * (ks & 1)][0];
    uint o1 = khalf ? u[ks >> 1][2 * (ks & 1) + 1][1] : u[ks >> 1][2 * (ks & 1)][1];
    uint g0 = got[ks >> 1][ks & 1][0];
    uint g1 = got[ks >> 1][ks & 1][1];
    az[ks].u.x = khalf ? g0 : o0;
    az[ks].u.y = khalf ? g1 : o1;
    az[ks].u.z = khalf ? o0 : g0;
    az[ks].u.w = khalf ? o1 : g1;
  }

  // ---- GEMM2 (normal): h_out = z @ W2 + b2 ----
  const uint4* W2v = (const uint4*)W2f;
  v16f acc2[4] = {};
#pragma unroll
  for (int c = 0; c < 4; c++)
#pragma unroll
    for (int ks = 0; ks < 8; ks++) {
      U b; b.u = W2v[((c * 8 + ks) << 6) + lane];
      acc2[c] = __builtin_amdgcn_mfma_f32_32x32x16_bf16(az[ks].s, b.s, acc2[c], 0, 0, 0);
    }

  float bv2[4];
#pragma unroll
  for (int c = 0; c < 4; c++) bv2[c] = b2[c * 32 + l31];
#pragma unroll
  for (int c = 0; c < 4; c++) {
    int col = c * 32 + l31;
#pragma unroll
    for (int r = 0; r < 16; r++) {
      int m = (r & 3) + 8 * (r >> 2) + 4 * khalf;
      t[(size_t)(rb + m) * HIDDEN + col] = (ushort)f2b(acc2[c][r] + bv2[c]);
    }
  }
}

// ---------------- fused pool+MLP: g = segsum(h); out = mlp(g) ----------------
__global__ __launch_bounds__(256) void poolmlp_k(const ushort* __restrict__ h,
                                                 const int* __restrict__ batch,
                                                 const float* __restrict__ W1, const float* __restrict__ b1,
                                                 const float* __restrict__ W2, const float* __restrict__ b2,
                                                 const float* __restrict__ W3, const float* __restrict__ b3,
                                                 float* __restrict__ out) {
  __shared__ int se[2];
  __shared__ float red[16][16][8];
  __shared__ float gl[128];
  __shared__ float r2[64];
  __shared__ float r3[32];
  int gi = blockIdx.x, tid = threadIdx.x;
  if (tid < 2) {
    int target = gi + tid;
    int lo = 0, hi = N_NODES;
    while (lo < hi) {
      int mid = (lo + hi) >> 1;
      if (batch[mid] < target) lo = mid + 1; else hi = mid;
    }
    se[tid] = lo;
  }
  __syncthreads();
  int start = se[0], end = se[1];
  int cg = tid & 15, rg = tid >> 4;
  float acc[8] = {0.f, 0.f, 0.f, 0.f, 0.f, 0.f, 0.f, 0.f};
  for (int r = start + rg; r < end; r += 16) {
    uint4 v = ((const uint4*)h)[r * 16 + cg];
    acc[0] += b2f_lo(v.x); acc[1] += b2f_hi(v.x);
    acc[2] += b2f_lo(v.y); acc[3] += b2f_hi(v.y);
    acc[4] += b2f_lo(v.z); acc[5] += b2f_hi(v.z);
    acc[6] += b2f_lo(v.w); acc[7] += b2f_hi(v.w);
  }
#pragma unroll
  for (int j = 0; j < 8; j++) red[rg][cg][j] = acc[j];
  __syncthreads();
  if (rg == 0) {
    float s[8];
#pragma unroll
    for (int j = 0; j < 8; j++) s[j] = red[0][cg][j];
#pragma unroll
    for (int i = 1; i < 16; i++)
#pragma unroll
      for (int j = 0; j < 8; j++) s[j] += red[i][cg][j];
#pragma unroll
    for (int j = 0; j < 8; j++) gl[cg * 8 + j] = s[j];
  }
  __syncthreads();
  if (tid < 64) {
    float s = b1[tid];
    for (int k = 0; k < 128; k++) s = fmaf(gl[k], W1[k * 64 + tid], s);
    r2[tid] = fmaxf(s, 0.f);
  }
  __syncthreads();
  if (tid < 32) {
    float s2 = b2[tid];
    for (int k = 0; k < 64; k++) s2 = fmaf(r2[k], W2[k * 32 + tid], s2);
    r3[tid] = fmaxf(s2, 0.f);
  }
  __syncthreads();
  if (tid < 64) {
    float pv = (tid < 32) ? r3[tid] * W3[tid] : 0.f;
#pragma unroll
    for (int off = 32; off > 0; off >>= 1) pv += __shfl_down(pv, off);
    if (tid == 0) out[gi] = pv + b3[0];
  }
}

extern "C" void kernel_launch(void* const* d_in, const int* in_sizes, int n_in,
                              void* d_out, int out_size, void* d_ws, size_t ws_size,
                              hipStream_t stream) {
  const int* x = (const int*)d_in[0];
  const int* src = (const int*)d_in[1];
  const int* dst = src + N_EDGES;
  const int* batch = (const int*)d_in[3];
  const float* node_emb = (const float*)d_in[4];
  const float* cW1 = (const float*)d_in[6];
  const float* cb1 = (const float*)d_in[7];
  const float* cW2 = (const float*)d_in[8];
  const float* cb2 = (const float*)d_in[9];
  const float* mW1 = (const float*)d_in[10];
  const float* mb1 = (const float*)d_in[11];
  const float* mW2 = (const float*)d_in[12];
  const float* mb2 = (const float*)d_in[13];
  const float* mW3 = (const float*)d_in[14];
  const float* mb3 = (const float*)d_in[15];
  float* out = (float*)d_out;

  char* p = (char*)d_ws;
  const size_t HB = (size_t)N_NODES * HIDDEN * sizeof(ushort);  // 25.6 MB
  ushort* h = (ushort*)p;      p += HB;
  ushort* t0 = (ushort*)p;     p += HB;
  ushort* Wtb = (ushort*)p;    p += (size_t)8 * 16384 * sizeof(ushort);
  int* cursor = (int*)p;       p += (size_t)N_NODES * sizeof(int);
  int* bins = (int*)p;         p += 64 * sizeof(int);
  int* slots = (int*)p;        p += (size_t)N_NODES * CAP * sizeof(int);
  int* perm = (int*)p;         p += (size_t)PADN * sizeof(int);

  (void)hipMemsetAsync(cursor, 0, ((size_t)N_NODES + 64) * sizeof(int), stream);  // cursor + bins
  prep_k<<<BUILD_BLKS + EMBED_BLKS + WT_BLKS, 256, 0, stream>>>(
      src, dst, cursor, slots, x, node_emb, h, cW1, cW2, Wtb);
  hist_k<<<PADN / 256, 256, 0, stream>>>(cursor, bins);
  scan_k<<<1, 64, 0, stream>>>(bins);
  scatter_k<<<PADN / 256, 256, 0, stream>>>(cursor, bins, perm);

  ushort* bufs[2] = {h, t0};
  for (int l = 0; l < 4; l++) {
    ushort* in = bufs[l & 1];
    ushort* tmp = bufs[(l & 1) ^ 1];
    agg_k<<<PADN / 32, 256, 0, stream>>>(in, cursor, slots, perm, tmp);
    gemm_k<<<N_NODES / 32, 64, 0, stream>>>(tmp,
                                            Wtb + (size_t)(2 * l) * 16384,
                                            Wtb + (size_t)(2 * l + 1) * 16384,
                                            cb1 + (size_t)l * HIDDEN,
                                            cb2 + (size_t)l * HIDDEN);
  }
  // after 4 layers output is back in h (bufs[0])
  poolmlp_k<<<NUM_GRAPHS, 256, 0, stream>>>(h, batch, mW1, mb1, mW2, mb2, mW3, mb3, out);
}

// Round 9
// 341.997 us; speedup vs baseline: 1.8750x; 1.0447x over previous
//
#include <hip/hip_runtime.h>

#define N_NODES 100000
#define N_EDGES 625000
#define HIDDEN 128
#define NUM_GRAPHS 512
#define CAP 40       // max in-degree capacity; Poisson(6.25) => P(deg>40) ~ e-43
#define PADN 100096  // multiple of 256; 3128 gather-chunks of 32

#define BUILD_BLKS4 611   // ceil(156250/256); 4 edges per thread (625000 = 4*156250)
#define EMBED_BLKS 6250   // N_NODES*16/256
#define WT_BLKS 64        // 8 mats x 8 chunks

typedef unsigned int uint;
typedef unsigned short ushort;
typedef short v8s __attribute__((ext_vector_type(8)));
typedef float v16f __attribute__((ext_vector_type(16)));

__device__ __forceinline__ float b2f_lo(uint u) { return __uint_as_float(u << 16); }
__device__ __forceinline__ float b2f_hi(uint u) { return __uint_as_float(u & 0xffff0000u); }
__device__ __forceinline__ uint f2b(float f) {  // RNE f32 -> bf16 bits
  uint u = __float_as_uint(f);
  return (u + 0x7fffu + ((u >> 16) & 1u)) >> 16;
}

// ---------------- fused prep: build adjacency + embed + weight-quantize ----------------
// R19: build phase does 4 edges/thread (int4 loads of src/dst, exact: 625000=4*156250)
// -> 4 independent atomicAdd+scatter chains per lane. prep was latency-bound on
// one ~400cy atomic round trip per lane (R8: 45us, 1.5TB/s, occ 63%); 4x MLP
// attacks exactly that. Slot arrival order changes (already nondeterministic).
__global__ __launch_bounds__(256) void prep_k(const int* __restrict__ src,
                                              const int* __restrict__ dst,
                                              int* __restrict__ cursor,
                                              int* __restrict__ slots,
                                              const int* __restrict__ x,
                                              const float* __restrict__ emb,
                                              ushort* __restrict__ h,
                                              const float* __restrict__ W1,
                                              const float* __restrict__ W2,
                                              ushort* __restrict__ Wt) {
  int blk = blockIdx.x;
  int tid = threadIdx.x;
  if (blk < BUILD_BLKS4) {
    int t = blk * 256 + tid;
    if (t < N_EDGES / 4) {
      int4 s4 = ((const int4*)src)[t];
      int4 d4 = ((const int4*)dst)[t];
      int p0 = atomicAdd(&cursor[d4.x], 1);
      int p1 = atomicAdd(&cursor[d4.y], 1);
      int p2 = atomicAdd(&cursor[d4.z], 1);
      int p3 = atomicAdd(&cursor[d4.w], 1);
      if (p0 < CAP) slots[(size_t)d4.x * CAP + p0] = s4.x;
      if (p1 < CAP) slots[(size_t)d4.y * CAP + p1] = s4.y;
      if (p2 < CAP) slots[(size_t)d4.z * CAP + p2] = s4.z;
      if (p3 < CAP) slots[(size_t)d4.w * CAP + p3] = s4.w;
    }
  } else if (blk < BUILD_BLKS4 + EMBED_BLKS) {
    int t = (blk - BUILD_BLKS4) * 256 + tid;  // one 8-col chunk per thread
    int n = t >> 4;
    if (n < N_NODES) {
      int c = t & 15;
      const float4* e4 = (const float4*)(emb + (size_t)x[n] * HIDDEN + c * 8);
      float4 a = e4[0], b = e4[1];
      uint4 o;
      o.x = f2b(a.x) | (f2b(a.y) << 16);
      o.y = f2b(a.z) | (f2b(a.w) << 16);
      o.z = f2b(b.x) | (f2b(b.y) << 16);
      o.w = f2b(b.z) | (f2b(b.w) << 16);
      ((uint4*)h)[t] = o;
    }
  } else {
    int wb = blk - BUILD_BLKS4 - EMBED_BLKS;  // 0..63
    int mat = wb >> 3, chunk = wb & 7;
    const float* W = ((mat & 1) ? W2 : W1) + (size_t)(mat >> 1) * 16384;
    ushort* o = Wt + (size_t)mat * 16384;
#pragma unroll
    for (int jj = 0; jj < 8; jj++) {
      int idx = chunk * 2048 + tid + 256 * jj;  // coalesced read W[k][n]
      int k = idx >> 7, n = idx & 127;
      int c = n >> 5, l31 = n & 31;
      int ks = k >> 4, khalf = (k >> 3) & 1, e = k & 7;
      // fragment-ordered: slot s=c*8+ks, lane=khalf*32+l31, elem e
      o[(((c * 8 + ks) << 6) + (khalf << 5) + l31) * 8 + e] = (ushort)f2b(W[idx]);
    }
  }
}

// ---------------- degree-grouped permutation, two-level (LDS-aggregated) ----------------
__global__ __launch_bounds__(256) void hist_k(const int* __restrict__ cursor,
                                              int* __restrict__ bins) {
  __shared__ int lb[CAP + 1];
  int tid = threadIdx.x;
  if (tid <= CAP) lb[tid] = 0;
  __syncthreads();
  int n = blockIdx.x * 256 + tid;
  if (n < N_NODES) {
    int d = cursor[n]; if (d > CAP) d = CAP;
    atomicAdd(&lb[d], 1);                     // LDS atomic: cheap
  }
  __syncthreads();
  if (tid <= CAP && lb[tid] > 0) atomicAdd(&bins[tid], lb[tid]);  // fire-and-forget
}

__global__ __launch_bounds__(64) void scan_k(int* __restrict__ bins) {
  int i = threadIdx.x;
  int c = (i <= CAP) ? bins[i] : 0;
  int incl = c;
#pragma unroll
  for (int off = 1; off < 64; off <<= 1) {
    int t = __shfl_up(incl, off, 64);
    if (i >= off) incl += t;
  }
  if (i <= CAP) bins[i] = incl - c;           // exclusive prefix
}

// LPT dispatch: perm REVERSED (descending degree) so deg-40 blocks launch first.
__global__ __launch_bounds__(256) void scatter_k(const int* __restrict__ cursor,
                                                 int* __restrict__ bins,
                                                 int* __restrict__ perm) {
  __shared__ int lb[CAP + 1];
  __shared__ int lbase[CAP + 1];
  int tid = threadIdx.x;
  if (tid <= CAP) lb[tid] = 0;
  __syncthreads();
  int n = blockIdx.x * 256 + tid;
  int d = 0, rank = 0;
  bool real = (n < N_NODES);
  if (real) {
    d = cursor[n]; if (d > CAP) d = CAP;
    rank = atomicAdd(&lb[d], 1);
  }
  __syncthreads();
  if (tid <= CAP) {
    int c = lb[tid];
    lbase[tid] = c > 0 ? atomicAdd(&bins[tid], c) : 0;
  }
  __syncthreads();
  if (real) perm[(N_NODES - 1) - (lbase[d] + rank)] = n;   // descending degree
  else if (n < PADN) perm[n] = 0;
}

// ---------------- fused layer: h_out = (relu((agg+h)@W1+b1))@W2 + b2 ----------------
// R0's proven config: ONE WAVE PER BLOCK (64 thr), 32 permuted rows, zero LDS,
// zero barriers; depth-2 A/B gather pipeline with sched_barrier(0) pinning
// loads above accumulates; W read as B-frags straight from global (L1/L2-hot).
union U { uint4 u; v8s s; };

__device__ __forceinline__ void loadrow(uint4 dst[8], const uint4* __restrict__ rowp,
                                        int khalf) {
#pragma unroll
  for (int ks = 0; ks < 8; ks++) dst[ks] = rowp[khalf + 2 * ks];
}

__device__ __forceinline__ void accum8(const uint4 u[8], float acc[8][8]) {
#pragma unroll
  for (int ks = 0; ks < 8; ks++) {
    acc[ks][0] += b2f_lo(u[ks].x); acc[ks][1] += b2f_hi(u[ks].x);
    acc[ks][2] += b2f_lo(u[ks].y); acc[ks][3] += b2f_hi(u[ks].y);
    acc[ks][4] += b2f_lo(u[ks].z); acc[ks][5] += b2f_hi(u[ks].z);
    acc[ks][6] += b2f_lo(u[ks].w); acc[ks][7] += b2f_hi(u[ks].w);
  }
}

__global__ __launch_bounds__(64, 3) void layer_k(const ushort* __restrict__ hin,
                                                 const int* __restrict__ cursor,
                                                 const int* __restrict__ slots,
                                                 const int* __restrict__ perm,
                                                 const ushort* __restrict__ W1f,
                                                 const ushort* __restrict__ W2f,
                                                 const float* __restrict__ b1,
                                                 const float* __restrict__ b2,
                                                 ushort* __restrict__ hout) {
  int lane = threadIdx.x;                     // 0..63
  int l31 = lane & 31;
  int khalf = lane >> 5;
  int tb = blockIdx.x * 32;                   // tile base in perm order
  int prow = perm[tb + l31];                  // true row this lane gathers
  bool valid = (tb + l31) < N_NODES;

  float acc[8][8];
#pragma unroll
  for (int ks = 0; ks < 8; ks++)
#pragma unroll
    for (int e = 0; e < 8; e++) acc[ks][e] = 0.f;

  const uint4* base = (const uint4*)hin;      // 16 uint4 per 128-col row
  uint4 A[8], B[8];
  loadrow(A, base + (size_t)prow * 16, khalf);          // self row -> A

  int deg = valid ? cursor[prow] : 0;
  if (deg > CAP) deg = CAP;
  const int* sl = slots + (size_t)prow * CAP;
  if (deg > 0) loadrow(B, base + (size_t)sl[0] * 16, khalf);   // nbr 0 -> B
  __builtin_amdgcn_sched_barrier(0);
  accum8(A, acc);                                       // self

  int j = 0;
  while (j + 2 <= deg) {
    loadrow(A, base + (size_t)sl[j + 1] * 16, khalf);   // nbr j+1 -> A
    __builtin_amdgcn_sched_barrier(0);
    accum8(B, acc);                                     // nbr j
    if (j + 2 < deg) loadrow(B, base + (size_t)sl[j + 2] * 16, khalf);  // nbr j+2 -> B
    __builtin_amdgcn_sched_barrier(0);
    accum8(A, acc);                                     // nbr j+1
    j += 2;
  }
  if (j < deg) accum8(B, acc);                          // last odd neighbor

  // round to bf16 A-frags (same rounding point as unfused t0 = bf16(agg+h))
  U afr[8];
#pragma unroll
  for (int ks = 0; ks < 8; ks++) {
    afr[ks].u.x = f2b(acc[ks][0]) | (f2b(acc[ks][1]) << 16);
    afr[ks].u.y = f2b(acc[ks][2]) | (f2b(acc[ks][3]) << 16);
    afr[ks].u.z = f2b(acc[ks][4]) | (f2b(acc[ks][5]) << 16);
    afr[ks].u.w = f2b(acc[ks][6]) | (f2b(acc[ks][7]) << 16);
  }

  // ---- GEMM1 (flipped): z^T = W1^T-as-A @ agg-as-B; lane = node row ----
  const uint4* W1v = (const uint4*)W1f;       // frag-ordered: slot*64 + lane
  v16f acc1[4] = {};
#pragma unroll
  for (int c = 0; c < 4; c++)
#pragma unroll
    for (int ks = 0; ks < 8; ks++) {
      U b; b.u = W1v[((c * 8 + ks) << 6) + lane];
      acc1[c] = __builtin_amdgcn_mfma_f32_32x32x16_bf16(b.s, afr[ks].s, acc1[c], 0, 0, 0);
    }

  // bias + relu + pack: lane holds z[r=l31][k'], k' = 32c + (reg&3) + 8*(reg>>2) + 4*khalf
  uint u[4][4][2];
#pragma unroll
  for (int c = 0; c < 4; c++)
#pragma unroll
    for (int b = 0; b < 4; b++)
#pragma unroll
      for (int ap = 0; ap < 2; ap++) {
        int r0 = 2 * ap + 4 * b, r1 = r0 + 1;
        float v0 = fmaxf(acc1[c][r0] + b1[c * 32 + 2 * ap + 8 * b + 4 * khalf], 0.f);
        float v1 = fmaxf(acc1[c][r1] + b1[c * 32 + 2 * ap + 1 + 8 * b + 4 * khalf], 0.f);
        u[c][b][ap] = f2b(v0) | (f2b(v1) << 16);
      }

  uint got[4][2][2];
#pragma unroll
  for (int c = 0; c < 4; c++)
#pragma unroll
    for (int bh = 0; bh < 2; bh++)
#pragma unroll
      for (int ap = 0; ap < 2; ap++) {
        uint send = khalf ? u[c][2 * bh][ap] : u[c][2 * bh + 1][ap];
        got[c][bh][ap] = __shfl_xor(send, 32, 64);
      }

  U az[8];
#pragma unroll
  for (int ks = 0; ks < 8; ks++) {
    uint o0 = khalf ? u[ks >> 1][2 * (ks & 1) + 1][0] : u[ks >> 1][2 * (ks & 1)][0];
    uint o1 = khalf ? u[ks >> 1][2 * (ks & 1) + 1][1] : u[ks >> 1][2 * (ks & 1)][1];
    uint g0 = got[ks >> 1][ks & 1][0];
    uint g1 = got[ks >> 1][ks & 1][1];
    az[ks].u.x = khalf ? g0 : o0;
    az[ks].u.y = khalf ? g1 : o1;
    az[ks].u.z = khalf ? o0 : g0;
    az[ks].u.w = khalf ? o1 : g1;
  }

  // ---- GEMM2 (normal): h_out = z @ W2 + b2 ----
  const uint4* W2v = (const uint4*)W2f;
  v16f acc2[4] = {};
#pragma unroll
  for (int c = 0; c < 4; c++)
#pragma unroll
    for (int ks = 0; ks < 8; ks++) {
      U b; b.u = W2v[((c * 8 + ks) << 6) + lane];
      acc2[c] = __builtin_amdgcn_mfma_f32_32x32x16_bf16(az[ks].s, b.s, acc2[c], 0, 0, 0);
    }

  int trow[16];
#pragma unroll
  for (int r = 0; r < 16; r++) {
    int m = (r & 3) + 8 * (r >> 2) + 4 * khalf;
    trow[r] = __shfl(prow, m, 64);
  }
  float bv2[4];
#pragma unroll
  for (int c = 0; c < 4; c++) bv2[c] = b2[c * 32 + l31];
#pragma unroll
  for (int c = 0; c < 4; c++) {
    int col = c * 32 + l31;
#pragma unroll
    for (int r = 0; r < 16; r++) {
      int m = (r & 3) + 8 * (r >> 2) + 4 * khalf;
      if (tb + m < N_NODES)
        hout[(size_t)trow[r] * HIDDEN + col] = (ushort)f2b(acc2[c][r] + bv2[c]);
    }
  }
}

// ---------------- fused pool+MLP: g = segsum(h); out = mlp(g) ----------------
__global__ __launch_bounds__(256) void poolmlp_k(const ushort* __restrict__ h,
                                                 const int* __restrict__ batch,
                                                 const float* __restrict__ W1, const float* __restrict__ b1,
                                                 const float* __restrict__ W2, const float* __restrict__ b2,
                                                 const float* __restrict__ W3, const float* __restrict__ b3,
                                                 float* __restrict__ out) {
  __shared__ int se[2];
  __shared__ float red[16][16][8];
  __shared__ float gl[128];
  __shared__ float r2[64];
  __shared__ float r3[32];
  int gi = blockIdx.x, tid = threadIdx.x;
  if (tid < 2) {
    int target = gi + tid;
    int lo = 0, hi = N_NODES;
    while (lo < hi) {
      int mid = (lo + hi) >> 1;
      if (batch[mid] < target) lo = mid + 1; else hi = mid;
    }
    se[tid] = lo;
  }
  __syncthreads();
  int start = se[0], end = se[1];
  int cg = tid & 15, rg = tid >> 4;
  float acc[8] = {0.f, 0.f, 0.f, 0.f, 0.f, 0.f, 0.f, 0.f};
  for (int r = start + rg; r < end; r += 16) {
    uint4 v = ((const uint4*)h)[r * 16 + cg];
    acc[0] += b2f_lo(v.x); acc[1] += b2f_hi(v.x);
    acc[2] += b2f_lo(v.y); acc[3] += b2f_hi(v.y);
    acc[4] += b2f_lo(v.z); acc[5] += b2f_hi(v.z);
    acc[6] += b2f_lo(v.w); acc[7] += b2f_hi(v.w);
  }
#pragma unroll
  for (int j = 0; j < 8; j++) red[rg][cg][j] = acc[j];
  __syncthreads();
  if (rg == 0) {
    float s[8];
#pragma unroll
    for (int j = 0; j < 8; j++) s[j] = red[0][cg][j];
#pragma unroll
    for (int i = 1; i < 16; i++)
#pragma unroll
      for (int j = 0; j < 8; j++) s[j] += red[i][cg][j];
#pragma unroll
    for (int j = 0; j < 8; j++) gl[cg * 8 + j] = s[j];
  }
  __syncthreads();
  if (tid < 64) {
    float s = b1[tid];
    for (int k = 0; k < 128; k++) s = fmaf(gl[k], W1[k * 64 + tid], s);
    r2[tid] = fmaxf(s, 0.f);
  }
  __syncthreads();
  if (tid < 32) {
    float s2 = b2[tid];
    for (int k = 0; k < 64; k++) s2 = fmaf(r2[k], W2[k * 32 + tid], s2);
    r3[tid] = fmaxf(s2, 0.f);
  }
  __syncthreads();
  if (tid < 64) {
    float pv = (tid < 32) ? r3[tid] * W3[tid] : 0.f;
#pragma unroll
    for (int off = 32; off > 0; off >>= 1) pv += __shfl_down(pv, off);
    if (tid == 0) out[gi] = pv + b3[0];
  }
}

extern "C" void kernel_launch(void* const* d_in, const int* in_sizes, int n_in,
                              void* d_out, int out_size, void* d_ws, size_t ws_size,
                              hipStream_t stream) {
  const int* x = (const int*)d_in[0];
  const int* src = (const int*)d_in[1];
  const int* dst = src + N_EDGES;
  const int* batch = (const int*)d_in[3];
  const float* node_emb = (const float*)d_in[4];
  const float* cW1 = (const float*)d_in[6];
  const float* cb1 = (const float*)d_in[7];
  const float* cW2 = (const float*)d_in[8];
  const float* cb2 = (const float*)d_in[9];
  const float* mW1 = (const float*)d_in[10];
  const float* mb1 = (const float*)d_in[11];
  const float* mW2 = (const float*)d_in[12];
  const float* mb2 = (const float*)d_in[13];
  const float* mW3 = (const float*)d_in[14];
  const float* mb3 = (const float*)d_in[15];
  float* out = (float*)d_out;

  char* p = (char*)d_ws;
  const size_t HB = (size_t)N_NODES * HIDDEN * sizeof(ushort);  // 25.6 MB
  ushort* h = (ushort*)p;      p += HB;
  ushort* t0 = (ushort*)p;     p += HB;
  ushort* Wtb = (ushort*)p;    p += (size_t)8 * 16384 * sizeof(ushort);
  int* cursor = (int*)p;       p += (size_t)N_NODES * sizeof(int);
  int* bins = (int*)p;         p += 64 * sizeof(int);
  int* slots = (int*)p;        p += (size_t)N_NODES * CAP * sizeof(int);
  int* perm = (int*)p;         p += (size_t)PADN * sizeof(int);

  (void)hipMemsetAsync(cursor, 0, ((size_t)N_NODES + 64) * sizeof(int), stream);  // cursor + bins
  prep_k<<<BUILD_BLKS4 + EMBED_BLKS + WT_BLKS, 256, 0, stream>>>(
      src, dst, cursor, slots, x, node_emb, h, cW1, cW2, Wtb);
  hist_k<<<PADN / 256, 256, 0, stream>>>(cursor, bins);
  scan_k<<<1, 64, 0, stream>>>(bins);
  scatter_k<<<PADN / 256, 256, 0, stream>>>(cursor, bins, perm);

  const int grid = PADN / 32;  // 3128 one-wave blocks
  ushort* bufs[2] = {h, t0};
  for (int l = 0; l < 4; l++) {
    layer_k<<<grid, 64, 0, stream>>>(bufs[l & 1], cursor, slots, perm,
                                     Wtb + (size_t)(2 * l) * 16384,
                                     Wtb + (size_t)(2 * l + 1) * 16384,
                                     cb1 + (size_t)l * HIDDEN,
                                     cb2 + (size_t)l * HIDDEN,
                                     bufs[(l & 1) ^ 1]);
  }
  // after 4 layers output is back in h (bufs[0])
  poolmlp_k<<<NUM_GRAPHS, 256, 0, stream>>>(h, batch, mW1, mb1, mW2, mb2, mW3, mb3, out);
}